// Round 7
// baseline (396.262 us; speedup 1.0000x reference)
//
#include <hip/hip_runtime.h>

#define B 2
#define L 2048
#define C 256
#define H 8
#define D 32
#define HB 16   // H*B
// 1/sqrt(32) * log2(e): scores computed in log2 domain so exp() is a bare
// v_exp_f32 (exp2). Softmax is invariant to the consistent rescale.
#define SCALE2 0.25503486f
// DIAGNOSTIC ROUND: every grid is replicated x9 (blockIdx % base). All
// kernels are idempotent (pure writes of identical values), so replicas
// are benign. dur = F + 5*o + 9*K  ->  K = (dur - 142)/8.
#define REP 9

using bf16x8 = __attribute__((ext_vector_type(8))) __bf16;
using f32x4  = __attribute__((ext_vector_type(4))) float;

// bare v_exp_f32 (2^x)
static __device__ inline float fexp2(float x) {
    return __builtin_amdgcn_exp2f(x);
}

// round-to-nearest-even f32 -> bf16 bits
static __device__ inline unsigned short f2bf(float f) {
    unsigned u = __float_as_uint(f);
    return (unsigned short)((u + 0x7fffu + ((u >> 16) & 1u)) >> 16);
}

// ---------------------------------------------------------------------------
// Kernel 1: prep. base grid = 256 blocks, 256 threads.
// ---------------------------------------------------------------------------
__global__ __launch_bounds__(256) void prep_kernel(
    const float* __restrict__ x,   // (B,L,C)
    const float* __restrict__ Wq,  // (C, 256)
    const float* __restrict__ Wk,  // (C, 256)
    const float* __restrict__ Wv,  // (C, H)
    const float* __restrict__ pe,  // (L, C)
    unsigned short* __restrict__ xq_bf,  // (4096, 256) bf16
    unsigned short* __restrict__ WqkT,   // (512, 256) bf16
    float* __restrict__ Vo)              // (HB, L)
{
    __shared__ float xsh[16][C];   // 16 KiB
    const int bid = blockIdx.x % 256;
    const int t = threadIdx.x;
    const int row0 = bid * 16;
    const int b = row0 >> 11;      // 16-row block never straddles batches

#pragma unroll
    for (int i = 0; i < 16; ++i) {
        const int row = row0 + i;
        const int l = row & (L - 1);
        const float xv = x[row * C + t];
        xsh[i][t] = xv;
        xq_bf[row * C + t] = f2bf(xv + pe[l * C + t]);
    }

    // weight transpose: c = bid, n = t and t+256
    {
        const int c = bid;
        WqkT[t * C + c]         = f2bf(Wq[c * 256 + t]);
        WqkT[(t + 256) * C + c] = f2bf(Wk[c * 256 + t]);
    }
    __syncthreads();

    // V gate (threads 0..127: i = t>>3, h = t&7)
    if (t < 128) {
        const int i = t >> 3, h = t & 7;
        float acc = 0.f;
#pragma unroll 4
        for (int c = 0; c < C; ++c) acc += xsh[i][c] * Wv[c * H + h];
        const int l = (row0 + i) & (L - 1);
        Vo[(h * B + b) * L + l] = acc;
    }
}

// ---------------------------------------------------------------------------
// Kernel 2: QK projection GEMM via MFMA. base grid = 512 blocks.
// ---------------------------------------------------------------------------
__global__ __launch_bounds__(256) void qkgemm_kernel(
    const __bf16* __restrict__ A,     // (4096, 256)
    const __bf16* __restrict__ Bw,    // (512, 256)
    const float* __restrict__ bq,     // (256,) flat h*D+d
    const float* __restrict__ bk,
    unsigned short* __restrict__ Qo,  // (HB, L, D) bf16
    unsigned short* __restrict__ Ko)  // (HB, L, D) bf16
{
    const int bid = blockIdx.x % 512;
    const int t = threadIdx.x;
    const int w = t >> 6, lane = t & 63;
    const int quad = lane >> 4, col = lane & 15;
    const int m0 = (bid >> 3) * 64 + w * 16;
    const int n0 = (bid & 7) * 64;

    const f32x4 zero = {0.f, 0.f, 0.f, 0.f};
    f32x4 acc[4] = {zero, zero, zero, zero};

#pragma unroll
    for (int ks = 0; ks < 8; ++ks) {
        const int c0 = ks * 32 + quad * 8;
        const bf16x8 af = *(const bf16x8*)(A + (m0 + col) * C + c0);
#pragma unroll
        for (int j = 0; j < 4; ++j) {
            const bf16x8 bf =
                *(const bf16x8*)(Bw + (n0 + j * 16 + col) * C + c0);
            acc[j] = __builtin_amdgcn_mfma_f32_16x16x32_bf16(af, bf, acc[j], 0, 0, 0);
        }
    }

#pragma unroll
    for (int j = 0; j < 4; ++j) {
        const int n_g = n0 + j * 16 + col;       // D col = lane&15
        const bool isQ = n_g < 256;              // wave-uniform (16-col groups)
        const int n2 = isQ ? n_g : n_g - 256;
        const int h = n2 >> 5, d = n2 & 31;
        const float bias = isQ ? bq[n2] : bk[n2];
        unsigned short* dst = isQ ? Qo : Ko;
#pragma unroll
        for (int r = 0; r < 4; ++r) {
            const int m_g = m0 + quad * 4 + r;   // D row = quad*4+r
            const int b = m_g >> 11, l = m_g & (L - 1);
            float v = acc[j][r] + bias;
            if (isQ) v *= SCALE2;
            dst[((size_t)(h * B + b) * L + l) * D + d] = f2bf(v);
        }
    }
}

// ---------------------------------------------------------------------------
// Kernel 3 (pass A): base grid = 1024 blocks.
// ---------------------------------------------------------------------------
__global__ __launch_bounds__(256) void passA_kernel(
    const __bf16* __restrict__ Qb, const __bf16* __restrict__ Kb,
    const float* __restrict__ V, float* __restrict__ G)
{
    __shared__ float lred[4][2][4][4][16];  // 8 KiB [wave][frag][quad][reg][col]
    const int bid = blockIdx.x % 1024;
    const int t = threadIdx.x;
    const int w = t >> 6, lane = t & 63;
    const int quad = lane >> 4, col = lane & 15;
    const int hb = bid >> 6, qb = bid & 63;
    const __bf16* Qp = Qb + (size_t)hb * L * D;
    const __bf16* Kp = Kb + (size_t)hb * L * D;

    bf16x8 qf[2];
#pragma unroll
    for (int f = 0; f < 2; ++f)
        qf[f] = *(const bf16x8*)(Qp + ((qb * 2 + f) * 16 + col) * D + quad * 8);

    const f32x4 zero = {0.f, 0.f, 0.f, 0.f};
    float lsum[2][4];
#pragma unroll
    for (int f = 0; f < 2; ++f)
#pragma unroll
        for (int r = 0; r < 4; ++r) lsum[f][r] = 0.f;

#pragma unroll 4
    for (int kt = 0; kt < 32; ++kt) {
        const bf16x8 kf =
            *(const bf16x8*)(Kp + ((w * 32 + kt) * 16 + col) * D + quad * 8);
#pragma unroll
        for (int f = 0; f < 2; ++f) {
            f32x4 a = __builtin_amdgcn_mfma_f32_16x16x32_bf16(qf[f], kf, zero, 0, 0, 0);
            lsum[f][0] += fexp2(a[0]);
            lsum[f][1] += fexp2(a[1]);
            lsum[f][2] += fexp2(a[2]);
            lsum[f][3] += fexp2(a[3]);
        }
    }
#pragma unroll
    for (int f = 0; f < 2; ++f)
#pragma unroll
        for (int r = 0; r < 4; ++r) lred[w][f][quad][r][col] = lsum[f][r];
    __syncthreads();
    if (t < 32) {   // q_local = t = f*16 + qd*4 + r
        const int f = t >> 4, rem = t & 15, qd = rem >> 2, r = rem & 3;
        float s = 0.f;
#pragma unroll
        for (int w2 = 0; w2 < 4; ++w2) {
            const float* p = &lred[w2][f][qd][r][0];
#pragma unroll
            for (int c2 = 0; c2 < 16; ++c2) s += p[c2];
        }
        const int qq = hb * L + qb * 32 + t;
        G[qq] = V[qq] / s;
    }
}

// ---------------------------------------------------------------------------
// Kernel 4 (pass B): base grid = 2048 blocks.
// ---------------------------------------------------------------------------
__global__ __launch_bounds__(256) void passB_kernel(
    const __bf16* __restrict__ Qb, const __bf16* __restrict__ Kb,
    const float* __restrict__ G, float* __restrict__ S)
{
    __shared__ float sred[4][16];
    const int bid = blockIdx.x % 2048;
    const int t = threadIdx.x;
    const int w = t >> 6, lane = t & 63;
    const int quad = lane >> 4, col = lane & 15;
    const int kt = bid & 127, hb = bid >> 7;
    const __bf16* Qp = Qb + (size_t)hb * L * D;
    const __bf16* Kp = Kb + (size_t)hb * L * D;
    const float* Gp = G + hb * L;

    const bf16x8 kf = *(const bf16x8*)(Kp + (kt * 16 + col) * D + quad * 8);
    const f32x4 zero = {0.f, 0.f, 0.f, 0.f};
    const int kidx = kt * 16 + col;

    float sacc = 0.f;
    for (int qt = kt + w; qt < 128; qt += 4) {
        const bf16x8 qf = *(const bf16x8*)(Qp + (qt * 16 + col) * D + quad * 8);
        f32x4 a = __builtin_amdgcn_mfma_f32_16x16x32_bf16(qf, kf, zero, 0, 0, 0);
        const float4 g = *(const float4*)(Gp + qt * 16 + quad * 4);
        const int qbase = qt * 16 + quad * 4;
        sacc += (qbase + 0 >= kidx) ? fexp2(a[0]) * g.x : 0.f;
        sacc += (qbase + 1 >= kidx) ? fexp2(a[1]) * g.y : 0.f;
        sacc += (qbase + 2 >= kidx) ? fexp2(a[2]) * g.z : 0.f;
        sacc += (qbase + 3 >= kidx) ? fexp2(a[3]) * g.w : 0.f;
    }
    sacc += __shfl_xor(sacc, 16, 64);   // sum the 4 quads (same col)
    sacc += __shfl_xor(sacc, 32, 64);
    if (lane < 16) sred[w][lane] = sacc;
    __syncthreads();
    if (t < 16)
        S[hb * L + kt * 16 + t] =
            sred[0][t] + sred[1][t] + sred[2][t] + sred[3][t];
}

// ---------------------------------------------------------------------------
// Kernel 5: pool. base grid = 128 blocks.
// ---------------------------------------------------------------------------
__global__ __launch_bounds__(256) void pool_kernel(
    const float* __restrict__ S, float* __restrict__ out)
{
    const int bid = blockIdx.x % 128;
    const int flat = bid * 256 + threadIdx.x;  // (b*L + k)*H + h
    const int h = flat & 7;
    const int k = (flat >> 3) & (L - 1);
    const int b = flat >> 14;
    const float* Sb = S + (h * B + b) * L;
    float s = Sb[k];
    float cnt = 1.f;
    if (k > 0)     { s += Sb[k - 1]; cnt += 1.f; }
    if (k < L - 1) { s += Sb[k + 1]; cnt += 1.f; }
    out[flat] = s / cnt;
}

// ---------------------------------------------------------------------------
extern "C" void kernel_launch(void* const* d_in, const int* in_sizes, int n_in,
                              void* d_out, int out_size, void* d_ws, size_t ws_size,
                              hipStream_t stream)
{
    const float* x  = (const float*)d_in[0];
    const float* Wq = (const float*)d_in[1];
    const float* bq = (const float*)d_in[2];
    const float* Wk = (const float*)d_in[3];
    const float* bk = (const float*)d_in[4];
    const float* Wv = (const float*)d_in[5];
    const float* pe = (const float*)d_in[6];
    float* out = (float*)d_out;

    unsigned short* xq_bf = (unsigned short*)d_ws;        // 4096*256   (2 MB)
    unsigned short* WqkT  = xq_bf + (size_t)4096 * C;     // 512*256    (256 KB)
    unsigned short* Qbf   = WqkT + (size_t)512 * C;       // HB*L*D     (2 MB)
    unsigned short* Kbf   = Qbf + (size_t)HB * L * D;     // HB*L*D     (2 MB)
    float* Vo = (float*)(Kbf + (size_t)HB * L * D);       // HB*L f32
    float* G  = Vo + (size_t)HB * L;
    float* S  = G  + (size_t)HB * L;

    prep_kernel<<<256 * REP, 256, 0, stream>>>(x, Wq, Wk, Wv, pe, xq_bf, WqkT, Vo);
    qkgemm_kernel<<<512 * REP, 256, 0, stream>>>(
        (const __bf16*)xq_bf, (const __bf16*)WqkT, bq, bk, Qbf, Kbf);
    passA_kernel<<<1024 * REP, 256, 0, stream>>>(
        (const __bf16*)Qbf, (const __bf16*)Kbf, Vo, G);
    passB_kernel<<<2048 * REP, 256, 0, stream>>>(
        (const __bf16*)Qbf, (const __bf16*)Kbf, G, S);
    pool_kernel<<<128 * REP, 256, 0, stream>>>(S, out);
}